// Round 3
// baseline (4687.703 us; speedup 1.0000x reference)
//
#include <hip/hip_runtime.h>
#include <math.h>

#define H 1024
#define SEQ 256
#define VOUT 32000

typedef unsigned long long u64;

__device__ __forceinline__ float sigmoidf_(float x) { return 1.f / (1.f + expf(-x)); }

// ---------------------------------------------------------------------------
// Tagged-slot dataflow sync: each cross-block value is an 8-byte slot packing
// {float value (lo 32), step tag (hi 32)} written by ONE producer thread with
// a single relaxed agent-scope 64-bit atomic store (single-copy atomic on
// 8B-aligned global). Consumers spin until the tag matches their step. This
// makes data arrival = synchronization: ONE LLC round trip per stage, vs the
// old barrier's leaf+root+gen chain (3-4 RTs). Tags increase monotonically
// (enc h: 1..256, dec h: 257..512, dec s/c: 1..256) so stale values (incl.
// the harness's 0xAA poison = tag 0xAAAAAAAA) never match.
// WAR safety: h slots are parity-double-buffered (one step of overlap);
// s/c slots are single-buffered — safe because any block's progress to the
// overwriting stage transitively requires EVERY block to have finished the
// reading stage (all-to-all dependence each step, per-block __syncthreads
// ties each block's publishes to its full poll set).
// ---------------------------------------------------------------------------
__device__ __forceinline__ u64 aload64(const u64* p) {
    return __hip_atomic_load(p, __ATOMIC_RELAXED, __HIP_MEMORY_SCOPE_AGENT);
}
__device__ __forceinline__ void publish(u64* p, float v, unsigned tag) {
    u64 pk = ((u64)tag << 32) | (u64)__float_as_uint(v);
    __hip_atomic_store(p, pk, __ATOMIC_RELAXED, __HIP_MEMORY_SCOPE_AGENT);
}
__device__ __forceinline__ float wait1(const u64* p, unsigned tag) {
    u64 v = aload64(p);
    while ((unsigned)(v >> 32) != tag) {
        __builtin_amdgcn_s_sleep(1);
        v = aload64(p);
    }
    return __uint_as_float((unsigned)v);
}
// Poll 4 slots with ILP: all four loads issue back-to-back each retry, so a
// retry costs ~1 LLC round trip, not 4.
__device__ __forceinline__ void wait4(const u64* p0, const u64* p1,
                                      const u64* p2, const u64* p3, unsigned tag,
                                      float& o0, float& o1, float& o2, float& o3) {
    u64 v0 = aload64(p0), v1 = aload64(p1), v2 = aload64(p2), v3 = aload64(p3);
    while ((unsigned)(v0 >> 32) != tag || (unsigned)(v1 >> 32) != tag ||
           (unsigned)(v2 >> 32) != tag || (unsigned)(v3 >> 32) != tag) {
        __builtin_amdgcn_s_sleep(1);
        v0 = aload64(p0); v1 = aload64(p1); v2 = aload64(p2); v3 = aload64(p3);
    }
    o0 = __uint_as_float((unsigned)v0);
    o1 = __uint_as_float((unsigned)v1);
    o2 = __uint_as_float((unsigned)v2);
    o3 = __uint_as_float((unsigned)v3);
}

// ---------------------------------------------------------------------------
__global__ __launch_bounds__(256) void gather_kernel(
    const int* __restrict__ input_ids, const int* __restrict__ target_ids,
    const float* __restrict__ enc_emb, const float* __restrict__ dec_emb,
    float* __restrict__ enc_x, float* __restrict__ dec_e)
{
    int b = blockIdx.x, tid = threadIdx.x;
    if (b < SEQ) {
        int tok = input_ids[b];
        const float4* src = (const float4*)(enc_emb + (size_t)tok * H);
        float4* dst = (float4*)(enc_x + (size_t)b * H);
        dst[tid] = src[tid];
    } else {
        int t = b - SEQ;
        int tok = (t == 0) ? 1 : target_ids[t - 1];
        const float4* src = (const float4*)(dec_emb + (size_t)tok * H);
        float4* dst = (float4*)(dec_e + (size_t)t * H);
        dst[tid] = src[tid];
    }
}

// h slots (2 parities x H) = 2048 u64: zero = {val 0.0f, tag 0} = enc step-0
// input. Re-run every launch (harness poisons d_ws with 0xAA).
__global__ __launch_bounds__(256) void init_kernel(u64* __restrict__ h64)
{
    int i = blockIdx.x * 256 + threadIdx.x;
    if (i < 2 * H) h64[i] = 0ULL;
}

// ---------------------------------------------------------------------------
// Generic NT GEMM: C[m,n] = sum_k A[m*lda+offa+k] * B[n*ldb+k] (+ bias[n])
// ---------------------------------------------------------------------------
__global__ __launch_bounds__(256) void gemm_nt_kernel(
    const float* __restrict__ A, const float* __restrict__ B,
    const float* __restrict__ bias, float* __restrict__ C,
    int Kdim, int lda, int offa, int ldb, int ldc)
{
    __shared__ float As[16][68];
    __shared__ float Bs[16][68];
    const int tid = threadIdx.x;
    const int m0 = blockIdx.y * 64;
    const int n0 = blockIdx.x * 64;
    const int tr = (tid >> 4) << 2;
    const int tc = (tid & 15) << 2;
    const int lrow = tid >> 2;
    const int lk = (tid & 3) << 2;
    const float* Ab = A + (size_t)m0 * lda + offa;
    const float* Bb = B + (size_t)n0 * ldb;
    float acc[4][4] = {{0.f,0.f,0.f,0.f},{0.f,0.f,0.f,0.f},{0.f,0.f,0.f,0.f},{0.f,0.f,0.f,0.f}};

    for (int k0 = 0; k0 < Kdim; k0 += 16) {
        float4 av = *(const float4*)(Ab + (size_t)lrow * lda + (k0 + lk));
        float4 bv = *(const float4*)(Bb + (size_t)lrow * ldb + (k0 + lk));
        As[lk + 0][lrow] = av.x; As[lk + 1][lrow] = av.y;
        As[lk + 2][lrow] = av.z; As[lk + 3][lrow] = av.w;
        Bs[lk + 0][lrow] = bv.x; Bs[lk + 1][lrow] = bv.y;
        Bs[lk + 2][lrow] = bv.z; Bs[lk + 3][lrow] = bv.w;
        __syncthreads();
#pragma unroll
        for (int k = 0; k < 16; ++k) {
            float4 a = *(const float4*)(&As[k][tr]);
            float4 b = *(const float4*)(&Bs[k][tc]);
            acc[0][0] = fmaf(a.x, b.x, acc[0][0]);
            acc[0][1] = fmaf(a.x, b.y, acc[0][1]);
            acc[0][2] = fmaf(a.x, b.z, acc[0][2]);
            acc[0][3] = fmaf(a.x, b.w, acc[0][3]);
            acc[1][0] = fmaf(a.y, b.x, acc[1][0]);
            acc[1][1] = fmaf(a.y, b.y, acc[1][1]);
            acc[1][2] = fmaf(a.y, b.z, acc[1][2]);
            acc[1][3] = fmaf(a.y, b.w, acc[1][3]);
            acc[2][0] = fmaf(a.z, b.x, acc[2][0]);
            acc[2][1] = fmaf(a.z, b.y, acc[2][1]);
            acc[2][2] = fmaf(a.z, b.z, acc[2][2]);
            acc[2][3] = fmaf(a.z, b.w, acc[2][3]);
            acc[3][0] = fmaf(a.w, b.x, acc[3][0]);
            acc[3][1] = fmaf(a.w, b.y, acc[3][1]);
            acc[3][2] = fmaf(a.w, b.z, acc[3][2]);
            acc[3][3] = fmaf(a.w, b.w, acc[3][3]);
        }
        __syncthreads();
    }
#pragma unroll
    for (int i = 0; i < 4; ++i) {
#pragma unroll
        for (int j = 0; j < 4; ++j) {
            float v = acc[i][j];
            if (bias) v += bias[n0 + tc + j];
            C[(size_t)(m0 + tr + i) * ldc + (n0 + tc + j)] = v;
        }
    }
}

// ---------------------------------------------------------------------------
// Encoder recurrence: wave w of block b owns unit u = b*4+w. NO barriers —
// step t polls h slots (parity t&1, tag t), computes, publishes h (parity
// (t+1)&1, tag t+1). LDS h_s double-buffered: a fast thread may overwrite
// the next parity while a sibling wave still reads the current one.
// ---------------------------------------------------------------------------
__global__ __launch_bounds__(256, 1) void enc_rnn_kernel(
    const float* __restrict__ Wh, const float* __restrict__ bh,
    const float* __restrict__ gi_all,
    u64* __restrict__ h64, float* __restrict__ encH)
{
    __shared__ float h_s[2][H];
    const int tid = threadIdx.x;
    const int wave = tid >> 6, lane = tid & 63;
    const int u = blockIdx.x * 4 + wave;

    float rWr[16], rWz[16], rWn[16];
    {
        const float* wr = Wh + (size_t)u * H;
        const float* wz = Wh + (size_t)(u + H) * H;
        const float* wn = Wh + (size_t)(u + 2 * H) * H;
#pragma unroll
        for (int i = 0; i < 16; ++i) {
            int k = lane + (i << 6);
            rWr[i] = wr[k]; rWz[i] = wz[k]; rWn[i] = wn[k];
        }
    }
    const float bhr = bh[u], bhz = bh[H + u], bhn = bh[2 * H + u];

    for (int t = 0; t < SEQ; ++t) {
        const int p = t & 1;
        // prefetch input-gate values first: these global loads overlap the poll
        const float g0 = gi_all[t * 3 * H + u];
        const float g1 = gi_all[t * 3 * H + H + u];
        const float g2 = gi_all[t * 3 * H + 2 * H + u];

        u64* hs = h64 + p * H;
        float f0, f1, f2, f3;
        wait4(hs + tid, hs + tid + 256, hs + tid + 512, hs + tid + 768,
              (unsigned)t, f0, f1, f2, f3);
        h_s[p][tid]       = f0;
        h_s[p][tid + 256] = f1;
        h_s[p][tid + 512] = f2;
        h_s[p][tid + 768] = f3;
        __syncthreads();

        float dr = 0.f, dz = 0.f, dn = 0.f;
#pragma unroll
        for (int i = 0; i < 16; ++i) {
            float hv = h_s[p][lane + (i << 6)];
            dr = fmaf(rWr[i], hv, dr);
            dz = fmaf(rWz[i], hv, dz);
            dn = fmaf(rWn[i], hv, dn);
        }
#pragma unroll
        for (int off = 32; off > 0; off >>= 1) {
            dr += __shfl_down(dr, off);
            dz += __shfl_down(dz, off);
            dn += __shfl_down(dn, off);
        }
        if (lane == 0) {
            float r = sigmoidf_(g0 + dr + bhr);
            float z = sigmoidf_(g1 + dz + bhz);
            float n = tanhf(g2 + r * (dn + bhn));
            float h2 = (1.f - z) * n + z * h_s[p][u];
            publish(h64 + ((t + 1) & 1) * H + u, h2, (unsigned)(t + 1));
            encH[(size_t)t * H + u] = h2;
        }
    }
}

// ---------------------------------------------------------------------------
// Decoder recurrence: 3 dataflow stages per step, zero barriers. h tags
// continue the encoder's chain (step t polls tag 256+t; enc left tag 256 in
// parity 0). s/c slots use tags 1..256. red4 (stage 1) and red4b (stage 2)
// are separate so stage-2 writers never race stage-1's tid0 reader.
// ---------------------------------------------------------------------------
__global__ __launch_bounds__(256, 1) void dec_rnn_kernel(
    const float* __restrict__ attn_W, const float* __restrict__ attn_e,
    const float* __restrict__ M, const float* __restrict__ comb_pre,
    const float* __restrict__ Wi, const float* __restrict__ Wh,
    const float* __restrict__ bi, const float* __restrict__ bh,
    u64* __restrict__ h64, u64* __restrict__ s64,
    u64* __restrict__ c64, float* __restrict__ hs_dec)
{
    __shared__ float h_s[2][H];
    __shared__ float c_s[H];
    __shared__ float a_s[SEQ];
    __shared__ float red4[4];
    __shared__ float red4b[4];
    const int b = blockIdx.x, tid = threadIdx.x;
    const int wave = tid >> 6, lane = tid & 63;
    const int u = b * 4 + wave;

    // ---- loop-invariant operands -> registers ----
    float rWir[16], rWiz[16], rWin[16], rWhr[16], rWhz[16], rWhn[16];
    {
        const float* wir = Wi + (size_t)u * H;
        const float* wiz = Wi + (size_t)(u + H) * H;
        const float* win = Wi + (size_t)(u + 2 * H) * H;
        const float* whr = Wh + (size_t)u * H;
        const float* whz = Wh + (size_t)(u + H) * H;
        const float* whn = Wh + (size_t)(u + 2 * H) * H;
#pragma unroll
        for (int i = 0; i < 16; ++i) {
            int k = lane + (i << 6);
            rWir[i] = wir[k]; rWiz[i] = wiz[k]; rWin[i] = win[k];
            rWhr[i] = whr[k]; rWhz[i] = whz[k]; rWhn[i] = whn[k];
        }
    }
    float rA[4];
    {
        const float* arow = attn_W + (size_t)b * (2 * H) + H;
#pragma unroll
        for (int j = 0; j < 4; ++j) rA[j] = arow[tid + (j << 8)];
    }
    float rM[4];
    {
        const float* Mrow = M + (size_t)u * SEQ;
#pragma unroll
        for (int j = 0; j < 4; ++j) rM[j] = Mrow[lane + (j << 6)];
    }
    const float bir = bi[u], biz = bi[H + u], bin_ = bi[2 * H + u];
    const float bhr = bh[u], bhz = bh[H + u], bhn = bh[2 * H + u];

    for (int t = 0; t < SEQ; ++t) {
        const int p = t & 1;
        const unsigned htag = (unsigned)(SEQ + t);
        const unsigned stag = (unsigned)(t + 1);
        // prefetch per-step constants first: they overlap the h poll
        const float aev  = attn_e[t * SEQ + b];
        const float cpre = comb_pre[t * H + u];

        u64* hs = h64 + p * H;
        float hr0, hr1, hr2, hr3;
        wait4(hs + tid, hs + tid + 256, hs + tid + 512, hs + tid + 768,
              htag, hr0, hr1, hr2, hr3);
        h_s[p][tid]       = hr0;
        h_s[p][tid + 256] = hr1;
        h_s[p][tid + 512] = hr2;
        h_s[p][tid + 768] = hr3;

        // ---- stage 1: score[b] = attn_e[t,b] + attn_W[b,H:] @ h ----
        float pp = fmaf(rA[0], hr0, 0.f);
        pp = fmaf(rA[1], hr1, pp);
        pp = fmaf(rA[2], hr2, pp);
        pp = fmaf(rA[3], hr3, pp);
#pragma unroll
        for (int off = 32; off > 0; off >>= 1) pp += __shfl_down(pp, off);
        if (lane == 0) red4[wave] = pp;
        __syncthreads();                 // red4 ready; h_s[p] visible for stage 3
        if (tid == 0)
            publish(s64 + b, red4[0] + red4[1] + red4[2] + red4[3] + aev, stag);

        // ---- stage 2: softmax (block-redundant) + c[u] ----
        float sv = wait1(s64 + tid, stag);
        float m = sv;
#pragma unroll
        for (int off = 32; off > 0; off >>= 1) m = fmaxf(m, __shfl_down(m, off));
        if (lane == 0) red4b[wave] = m;
        __syncthreads();
        float mx = fmaxf(fmaxf(red4b[0], red4b[1]), fmaxf(red4b[2], red4b[3]));
        float ev = expf(sv - mx);
        a_s[tid] = ev;
        float ssum = ev;
#pragma unroll
        for (int off = 32; off > 0; off >>= 1) ssum += __shfl_down(ssum, off);
        __syncthreads();                 // readers of red4b (mx) done; a_s visible
        if (lane == 0) red4b[wave] = ssum;
        __syncthreads();
        float inv = 1.f / (red4b[0] + red4b[1] + red4b[2] + red4b[3]);
        float pc = fmaf(a_s[lane], rM[0], 0.f);
        pc = fmaf(a_s[lane + 64],  rM[1], pc);
        pc = fmaf(a_s[lane + 128], rM[2], pc);
        pc = fmaf(a_s[lane + 192], rM[3], pc);
#pragma unroll
        for (int off = 32; off > 0; off >>= 1) pc += __shfl_down(pc, off);
        if (lane == 0)
            publish(c64 + u, fmaxf(0.f, cpre + pc * inv), stag);

        // ---- stage 3: GRU cell ----
        float c0, c1, c2, c3;
        wait4(c64 + tid, c64 + tid + 256, c64 + tid + 512, c64 + tid + 768,
              stag, c0, c1, c2, c3);
        c_s[tid]       = c0;
        c_s[tid + 256] = c1;
        c_s[tid + 512] = c2;
        c_s[tid + 768] = c3;
        __syncthreads();
        float dir = 0.f, diz = 0.f, din = 0.f, dhr = 0.f, dhz = 0.f, dhn = 0.f;
#pragma unroll
        for (int i = 0; i < 16; ++i) {
            int k = lane + (i << 6);
            float cv = c_s[k], hv = h_s[p][k];
            dir = fmaf(rWir[i], cv, dir);
            diz = fmaf(rWiz[i], cv, diz);
            din = fmaf(rWin[i], cv, din);
            dhr = fmaf(rWhr[i], hv, dhr);
            dhz = fmaf(rWhz[i], hv, dhz);
            dhn = fmaf(rWhn[i], hv, dhn);
        }
#pragma unroll
        for (int off = 32; off > 0; off >>= 1) {
            dir += __shfl_down(dir, off); diz += __shfl_down(diz, off);
            din += __shfl_down(din, off); dhr += __shfl_down(dhr, off);
            dhz += __shfl_down(dhz, off); dhn += __shfl_down(dhn, off);
        }
        if (lane == 0) {
            float r = sigmoidf_(dir + bir + dhr + bhr);
            float z = sigmoidf_(diz + biz + dhz + bhz);
            float n = tanhf(din + bin_ + r * (dhn + bhn));
            float h2 = (1.f - z) * n + z * h_s[p][u];
            publish(h64 + ((t + 1) & 1) * H + u, h2, htag + 1);
            hs_dec[(size_t)t * H + u] = h2;
        }
    }
}

// ---------------------------------------------------------------------------
__global__ __launch_bounds__(256) void nll_kernel(
    const float* __restrict__ logits, const int* __restrict__ target_ids,
    float* __restrict__ nll)
{
    const int t = blockIdx.x, tid = threadIdx.x;
    __shared__ float red[256];
    const float* row = logits + (size_t)t * VOUT;
    float mx = -1e30f;
    for (int i = tid; i < VOUT; i += 256) mx = fmaxf(mx, row[i]);
    red[tid] = mx;
    __syncthreads();
    for (int off = 128; off > 0; off >>= 1) {
        if (tid < off) red[tid] = fmaxf(red[tid], red[tid + off]);
        __syncthreads();
    }
    mx = red[0];
    __syncthreads();
    float s = 0.f;
    for (int i = tid; i < VOUT; i += 256) s += expf(row[i] - mx);
    red[tid] = s;
    __syncthreads();
    for (int off = 128; off > 0; off >>= 1) {
        if (tid < off) red[tid] += red[tid + off];
        __syncthreads();
    }
    if (tid == 0) {
        float lse = mx + logf(red[0]);
        nll[t] = lse - row[target_ids[t]];
    }
}

__global__ __launch_bounds__(256) void sum_kernel(
    const float* __restrict__ nll, float* __restrict__ out)
{
    __shared__ float red[256];
    int tid = threadIdx.x;
    red[tid] = nll[tid];
    __syncthreads();
    for (int off = 128; off > 0; off >>= 1) {
        if (tid < off) red[tid] += red[tid + off];
        __syncthreads();
    }
    if (tid == 0) out[0] = red[0];
}

// ---------------------------------------------------------------------------
extern "C" void kernel_launch(void* const* d_in, const int* in_sizes, int n_in,
                              void* d_out, int out_size, void* d_ws, size_t ws_size,
                              hipStream_t stream)
{
    const int*   input_ids  = (const int*)d_in[0];
    const int*   target_ids = (const int*)d_in[1];
    const float* enc_emb = (const float*)d_in[2];
    const float* enc_Wi  = (const float*)d_in[3];
    const float* enc_Wh  = (const float*)d_in[4];
    const float* enc_bi  = (const float*)d_in[5];
    const float* enc_bh  = (const float*)d_in[6];
    const float* dec_emb = (const float*)d_in[7];
    const float* dec_Wi  = (const float*)d_in[8];
    const float* dec_Wh  = (const float*)d_in[9];
    const float* dec_bi  = (const float*)d_in[10];
    const float* dec_bh  = (const float*)d_in[11];
    const float* attn_W  = (const float*)d_in[12];
    const float* attn_b  = (const float*)d_in[13];
    const float* comb_W  = (const float*)d_in[14];
    const float* comb_b  = (const float*)d_in[15];
    const float* out_W   = (const float*)d_in[16];
    const float* out_b   = (const float*)d_in[17];
    float* out = (float*)d_out;

    float* ws = (float*)d_ws;
    float* enc_x    = ws; ws += SEQ * H;
    float* dec_e    = ws; ws += SEQ * H;
    float* enc_gi   = ws; ws += SEQ * 3 * H;
    float* attn_e   = ws; ws += SEQ * SEQ;
    float* comb_pre = ws; ws += SEQ * H;
    float* Mmat     = ws; ws += H * SEQ;
    float* encH     = ws; ws += SEQ * H;
    float* hs_dec   = ws; ws += SEQ * H;
    u64*   h64      = (u64*)ws; ws += 2 * H * 2;   // 2048 u64 (2 parities x H)
    u64*   s64      = (u64*)ws; ws += SEQ * 2;     // 256 u64
    u64*   c64      = (u64*)ws; ws += H * 2;       // 1024 u64
    float* nll      = ws; ws += SEQ;
    ws += (256 - ((ws - (float*)d_ws) & 255)) & 255;
    float* logits   = ws; ws += (size_t)SEQ * VOUT;

    // phase 0: gathers + init h slots (tag 0 = initial zero hidden state)
    hipLaunchKernelGGL(gather_kernel, dim3(512), dim3(256), 0, stream,
                       input_ids, target_ids, enc_emb, dec_emb, enc_x, dec_e);
    hipLaunchKernelGGL(init_kernel, dim3(8), dim3(256), 0, stream, h64);

    // phase 1: batched pre-GEMMs
    hipLaunchKernelGGL(gemm_nt_kernel, dim3(3 * H / 64, SEQ / 64), dim3(256), 0, stream,
                       enc_x, enc_Wi, enc_bi, enc_gi, H, H, 0, H, 3 * H);
    hipLaunchKernelGGL(gemm_nt_kernel, dim3(SEQ / 64, SEQ / 64), dim3(256), 0, stream,
                       dec_e, attn_W, attn_b, attn_e, H, H, 0, 2 * H, SEQ);
    hipLaunchKernelGGL(gemm_nt_kernel, dim3(H / 64, SEQ / 64), dim3(256), 0, stream,
                       dec_e, comb_W, comb_b, comb_pre, H, H, 0, 2 * H, H);

    // phase 2: encoder recurrence (cooperative launch for residency guarantee)
    {
        void* args[] = {(void*)&enc_Wh, (void*)&enc_bh, (void*)&enc_gi,
                        (void*)&h64, (void*)&encH};
        hipLaunchCooperativeKernel((void*)enc_rnn_kernel, dim3(256), dim3(256),
                                   args, 0, stream);
    }

    // phase 2.5: M = comb_W[:,H:] @ encH^T
    hipLaunchKernelGGL(gemm_nt_kernel, dim3(SEQ / 64, H / 64), dim3(256), 0, stream,
                       comb_W, encH, (const float*)nullptr, Mmat, H, 2 * H, H, H, SEQ);

    // phase 3: decoder recurrence (h tags continue at 256 from encoder)
    {
        void* args[] = {(void*)&attn_W, (void*)&attn_e, (void*)&Mmat, (void*)&comb_pre,
                        (void*)&dec_Wi, (void*)&dec_Wh, (void*)&dec_bi, (void*)&dec_bh,
                        (void*)&h64, (void*)&s64, (void*)&c64, (void*)&hs_dec};
        hipLaunchCooperativeKernel((void*)dec_rnn_kernel, dim3(256), dim3(256),
                                   args, 0, stream);
    }

    // phase 4: logits = hs_dec @ out_W^T + out_b
    hipLaunchKernelGGL(gemm_nt_kernel, dim3(VOUT / 64, SEQ / 64), dim3(256), 0, stream,
                       hs_dec, out_W, out_b, logits, H, H, 0, H, VOUT);

    // phase 5: NLL + total
    hipLaunchKernelGGL(nll_kernel, dim3(SEQ), dim3(256), 0, stream,
                       logits, target_ids, nll);
    hipLaunchKernelGGL(sum_kernel, dim3(1), dim3(256), 0, stream, nll, out);
}

// Round 5
// 4321.268 us; speedup vs baseline: 1.0848x; 1.0848x over previous
//
#include <hip/hip_runtime.h>
#include <math.h>

#define H 1024
#define SEQ 256
#define VOUT 32000

typedef unsigned long long u64;

__device__ __forceinline__ float sigmoidf_(float x) { return 1.f / (1.f + expf(-x)); }

// ---------------------------------------------------------------------------
// Tagged-slot dataflow sync: each cross-block value is an 8-byte slot packing
// {float value (lo 32), step tag (hi 32)} written by ONE producer thread with
// a single relaxed agent-scope 64-bit atomic store. Consumers verify tags
// before use, so data arrival IS synchronization (no barrier tree). Tags
// increase monotonically (enc h: 1..256, dec h: 257..512, dec s/c: 1..256)
// so stale values (incl. the 0xAA workspace poison = tag 0xAAAAAAAA) never
// match.
//
// Two-level wait discipline (lesson from the round-3 poll storm, which put
// ~2048 pollers on every slot line and delayed publish visibility to ~3us):
//  1) CANARY: 1-4 threads/block poll one canary slot per 256-slot group
//     (256 pollers/line, like a barrier gen word). Canary slots are a subset
//     of the block's wait-set, so no new dependence edges -> no deadlock.
//  2) COHORT PULL: all 256 threads issue ONE ILP round of tagged loads, then
//     a single __syncthreads_and decides uniformly whether to retry (with
//     backoff). Fast path = exactly one round trip; retry path is paced by
//     the whole block (~1us), not per-thread tight spins.
//
// WAR safety: h slots are parity-double-buffered (one step of overlap);
// s/c slots are single-buffered - safe because any block's progress to the
// overwriting stage transitively requires EVERY block to have finished the
// reading stage (all-to-all dependence each step).
// ---------------------------------------------------------------------------
__device__ __forceinline__ u64 aload64(const u64* p) {
    return __hip_atomic_load(p, __ATOMIC_RELAXED, __HIP_MEMORY_SCOPE_AGENT);
}
__device__ __forceinline__ void publish(u64* p, float v, unsigned tag) {
    u64 pk = ((u64)tag << 32) | (u64)__float_as_uint(v);
    __hip_atomic_store(p, pk, __ATOMIC_RELAXED, __HIP_MEMORY_SCOPE_AGENT);
}
__device__ __forceinline__ void waittag(const u64* p, unsigned tag) {
    while ((unsigned)(aload64(p) >> 32) != tag) __builtin_amdgcn_s_sleep(1);
}
// Cohort-verified pull of 4 slots. MUST be called by all 256 threads.
__device__ __forceinline__ void cohort_pull4(
    const u64* p0, const u64* p1, const u64* p2, const u64* p3, unsigned tag,
    float& o0, float& o1, float& o2, float& o3)
{
    for (;;) {
        u64 v0 = aload64(p0), v1 = aload64(p1), v2 = aload64(p2), v3 = aload64(p3);
        int ok = ((unsigned)(v0 >> 32) == tag) & ((unsigned)(v1 >> 32) == tag) &
                 ((unsigned)(v2 >> 32) == tag) & ((unsigned)(v3 >> 32) == tag);
        if (__syncthreads_and(ok)) {
            o0 = __uint_as_float((unsigned)v0);
            o1 = __uint_as_float((unsigned)v1);
            o2 = __uint_as_float((unsigned)v2);
            o3 = __uint_as_float((unsigned)v3);
            return;
        }
        __builtin_amdgcn_s_sleep(2);
    }
}
// Cohort-verified pull of 1 slot. MUST be called by all 256 threads.
__device__ __forceinline__ float cohort_pull1(const u64* p, unsigned tag)
{
    for (;;) {
        u64 v = aload64(p);
        int ok = ((unsigned)(v >> 32) == tag);
        if (__syncthreads_and(ok)) return __uint_as_float((unsigned)v);
        __builtin_amdgcn_s_sleep(2);
    }
}

// ---------------------------------------------------------------------------
__global__ __launch_bounds__(256) void gather_kernel(
    const int* __restrict__ input_ids, const int* __restrict__ target_ids,
    const float* __restrict__ enc_emb, const float* __restrict__ dec_emb,
    float* __restrict__ enc_x, float* __restrict__ dec_e)
{
    int b = blockIdx.x, tid = threadIdx.x;
    if (b < SEQ) {
        int tok = input_ids[b];
        const float4* src = (const float4*)(enc_emb + (size_t)tok * H);
        float4* dst = (float4*)(enc_x + (size_t)b * H);
        dst[tid] = src[tid];
    } else {
        int t = b - SEQ;
        int tok = (t == 0) ? 1 : target_ids[t - 1];
        const float4* src = (const float4*)(dec_emb + (size_t)tok * H);
        float4* dst = (float4*)(dec_e + (size_t)t * H);
        dst[tid] = src[tid];
    }
}

// h slots (2 parities x H) = 2048 u64: zero = {val 0.0f, tag 0} = enc step-0
// input. Re-run every launch (harness poisons d_ws with 0xAA).
__global__ __launch_bounds__(256) void init_kernel(u64* __restrict__ h64)
{
    int i = blockIdx.x * 256 + threadIdx.x;
    if (i < 2 * H) h64[i] = 0ULL;
}

// ---------------------------------------------------------------------------
// NT GEMM, 128x64 tile, 8x4 acc/thread: C[m,n] = sum_k A[m*lda+offa+k]*B[n*ldb+k]
// (+ bias[n]). Per-element k-order identical to the old 64x64 kernel
// (sequential fmaf over k0-tiles of 16), so results are bitwise unchanged.
// ---------------------------------------------------------------------------
__global__ __launch_bounds__(256) void gemm_nt_kernel(
    const float* __restrict__ A, const float* __restrict__ B,
    const float* __restrict__ bias, float* __restrict__ C,
    int Kdim, int lda, int offa, int ldb, int ldc)
{
    __shared__ float As[16][136];
    __shared__ float Bs[16][68];
    const int tid = threadIdx.x;
    const int m0 = blockIdx.y * 128;
    const int n0 = blockIdx.x * 64;
    const int tr = (tid >> 4) << 3;   // 0..120 step 8
    const int tc = (tid & 15) << 2;   // 0..60 step 4
    const int lrow = tid >> 2;        // 0..63
    const int lk = (tid & 3) << 2;    // 0,4,8,12
    const float* Ab = A + (size_t)m0 * lda + offa;
    const float* Bb = B + (size_t)n0 * ldb;
    float acc[8][4];
#pragma unroll
    for (int i = 0; i < 8; ++i)
#pragma unroll
        for (int j = 0; j < 4; ++j) acc[i][j] = 0.f;

    for (int k0 = 0; k0 < Kdim; k0 += 16) {
        float4 a0 = *(const float4*)(Ab + (size_t)lrow * lda + (k0 + lk));
        float4 a1 = *(const float4*)(Ab + (size_t)(lrow + 64) * lda + (k0 + lk));
        float4 bv = *(const float4*)(Bb + (size_t)lrow * ldb + (k0 + lk));
        As[lk + 0][lrow] = a0.x; As[lk + 1][lrow] = a0.y;
        As[lk + 2][lrow] = a0.z; As[lk + 3][lrow] = a0.w;
        As[lk + 0][lrow + 64] = a1.x; As[lk + 1][lrow + 64] = a1.y;
        As[lk + 2][lrow + 64] = a1.z; As[lk + 3][lrow + 64] = a1.w;
        Bs[lk + 0][lrow] = bv.x; Bs[lk + 1][lrow] = bv.y;
        Bs[lk + 2][lrow] = bv.z; Bs[lk + 3][lrow] = bv.w;
        __syncthreads();
#pragma unroll
        for (int k = 0; k < 16; ++k) {
            float4 aA = *(const float4*)(&As[k][tr]);
            float4 aB = *(const float4*)(&As[k][tr + 4]);
            float4 b  = *(const float4*)(&Bs[k][tc]);
            float a8[8] = {aA.x, aA.y, aA.z, aA.w, aB.x, aB.y, aB.z, aB.w};
            float b4[4] = {b.x, b.y, b.z, b.w};
#pragma unroll
            for (int i = 0; i < 8; ++i)
#pragma unroll
                for (int j = 0; j < 4; ++j)
                    acc[i][j] = fmaf(a8[i], b4[j], acc[i][j]);
        }
        __syncthreads();
    }
#pragma unroll
    for (int i = 0; i < 8; ++i) {
#pragma unroll
        for (int j = 0; j < 4; ++j) {
            float v = acc[i][j];
            if (bias) v += bias[n0 + tc + j];
            C[(size_t)(m0 + tr + i) * ldc + (n0 + tc + j)] = v;
        }
    }
}

// ---------------------------------------------------------------------------
// Encoder recurrence: wave w of block b owns unit u = b*4+w. NO barriers —
// step t: canary-wait, cohort pull (parity t&1, tag t), compute, publish
// (parity (t+1)&1, tag t+1). LDS h_s double-buffered across steps.
// ---------------------------------------------------------------------------
__global__ __launch_bounds__(256, 1) void enc_rnn_kernel(
    const float* __restrict__ Wh, const float* __restrict__ bh,
    const float* __restrict__ gi_all,
    u64* __restrict__ h64, float* __restrict__ encH)
{
    __shared__ float h_s[2][H];
    const int tid = threadIdx.x;
    const int wave = tid >> 6, lane = tid & 63;
    const int u = blockIdx.x * 4 + wave;

    float rWr[16], rWz[16], rWn[16];
    {
        const float* wr = Wh + (size_t)u * H;
        const float* wz = Wh + (size_t)(u + H) * H;
        const float* wn = Wh + (size_t)(u + 2 * H) * H;
#pragma unroll
        for (int i = 0; i < 16; ++i) {
            int k = lane + (i << 6);
            rWr[i] = wr[k]; rWz[i] = wz[k]; rWn[i] = wn[k];
        }
    }
    const float bhr = bh[u], bhz = bh[H + u], bhn = bh[2 * H + u];

    for (int t = 0; t < SEQ; ++t) {
        const int p = t & 1;
        // prefetch input-gate values first: these global loads overlap the wait
        const float g0 = gi_all[t * 3 * H + u];
        const float g1 = gi_all[t * 3 * H + H + u];
        const float g2 = gi_all[t * 3 * H + 2 * H + u];

        u64* hs = h64 + p * H;
        if (tid < 4) waittag(hs + 255 + (tid << 8), (unsigned)t);
        __syncthreads();
        float f0, f1, f2, f3;
        cohort_pull4(hs + tid, hs + tid + 256, hs + tid + 512, hs + tid + 768,
                     (unsigned)t, f0, f1, f2, f3);
        h_s[p][tid]       = f0;
        h_s[p][tid + 256] = f1;
        h_s[p][tid + 512] = f2;
        h_s[p][tid + 768] = f3;
        __syncthreads();

        float dr = 0.f, dz = 0.f, dn = 0.f;
#pragma unroll
        for (int i = 0; i < 16; ++i) {
            float hv = h_s[p][lane + (i << 6)];
            dr = fmaf(rWr[i], hv, dr);
            dz = fmaf(rWz[i], hv, dz);
            dn = fmaf(rWn[i], hv, dn);
        }
#pragma unroll
        for (int off = 32; off > 0; off >>= 1) {
            dr += __shfl_down(dr, off);
            dz += __shfl_down(dz, off);
            dn += __shfl_down(dn, off);
        }
        if (lane == 0) {
            float r = sigmoidf_(g0 + dr + bhr);
            float z = sigmoidf_(g1 + dz + bhz);
            float n = tanhf(g2 + r * (dn + bhn));
            float h2 = (1.f - z) * n + z * h_s[p][u];
            publish(h64 + ((t + 1) & 1) * H + u, h2, (unsigned)(t + 1));
            encH[(size_t)t * H + u] = h2;
        }
    }
}

// ---------------------------------------------------------------------------
// Decoder recurrence: 3 dataflow stages per step, zero barriers, canary +
// cohort pull per stage. h tags continue the encoder's chain (step t polls
// tag 256+t; enc left tag 256 in parity 0). s/c slots use tags 1..256.
// red4/red4b separated so stage-2 writers never race stage-1's tid0 reader.
// ---------------------------------------------------------------------------
__global__ __launch_bounds__(256, 1) void dec_rnn_kernel(
    const float* __restrict__ attn_W, const float* __restrict__ attn_e,
    const float* __restrict__ M, const float* __restrict__ comb_pre,
    const float* __restrict__ Wi, const float* __restrict__ Wh,
    const float* __restrict__ bi, const float* __restrict__ bh,
    u64* __restrict__ h64, u64* __restrict__ s64,
    u64* __restrict__ c64, float* __restrict__ hs_dec)
{
    __shared__ float h_s[2][H];
    __shared__ float c_s[H];
    __shared__ float a_s[SEQ];
    __shared__ float red4[4];
    __shared__ float red4b[4];
    const int b = blockIdx.x, tid = threadIdx.x;
    const int wave = tid >> 6, lane = tid & 63;
    const int u = b * 4 + wave;

    // ---- loop-invariant operands -> registers ----
    float rWir[16], rWiz[16], rWin[16], rWhr[16], rWhz[16], rWhn[16];
    {
        const float* wir = Wi + (size_t)u * H;
        const float* wiz = Wi + (size_t)(u + H) * H;
        const float* win = Wi + (size_t)(u + 2 * H) * H;
        const float* whr = Wh + (size_t)u * H;
        const float* whz = Wh + (size_t)(u + H) * H;
        const float* whn = Wh + (size_t)(u + 2 * H) * H;
#pragma unroll
        for (int i = 0; i < 16; ++i) {
            int k = lane + (i << 6);
            rWir[i] = wir[k]; rWiz[i] = wiz[k]; rWin[i] = win[k];
            rWhr[i] = whr[k]; rWhz[i] = whz[k]; rWhn[i] = whn[k];
        }
    }
    float rA[4];
    {
        const float* arow = attn_W + (size_t)b * (2 * H) + H;
#pragma unroll
        for (int j = 0; j < 4; ++j) rA[j] = arow[tid + (j << 8)];
    }
    float rM[4];
    {
        const float* Mrow = M + (size_t)u * SEQ;
#pragma unroll
        for (int j = 0; j < 4; ++j) rM[j] = Mrow[lane + (j << 6)];
    }
    const float bir = bi[u], biz = bi[H + u], bin_ = bi[2 * H + u];
    const float bhr = bh[u], bhz = bh[H + u], bhn = bh[2 * H + u];

    for (int t = 0; t < SEQ; ++t) {
        const int p = t & 1;
        const unsigned htag = (unsigned)(SEQ + t);
        const unsigned stag = (unsigned)(t + 1);
        // prefetch per-step constants first: they overlap the h wait
        const float aev  = attn_e[t * SEQ + b];
        const float cpre = comb_pre[t * H + u];

        u64* hs = h64 + p * H;
        if (tid < 4) waittag(hs + 255 + (tid << 8), htag);
        __syncthreads();
        float hr0, hr1, hr2, hr3;
        cohort_pull4(hs + tid, hs + tid + 256, hs + tid + 512, hs + tid + 768,
                     htag, hr0, hr1, hr2, hr3);
        h_s[p][tid]       = hr0;
        h_s[p][tid + 256] = hr1;
        h_s[p][tid + 512] = hr2;
        h_s[p][tid + 768] = hr3;

        // ---- stage 1: score[b] = attn_e[t,b] + attn_W[b,H:] @ h ----
        float pp = fmaf(rA[0], hr0, 0.f);
        pp = fmaf(rA[1], hr1, pp);
        pp = fmaf(rA[2], hr2, pp);
        pp = fmaf(rA[3], hr3, pp);
#pragma unroll
        for (int off = 32; off > 0; off >>= 1) pp += __shfl_down(pp, off);
        if (lane == 0) red4[wave] = pp;
        __syncthreads();                 // red4 ready; h_s[p] visible for stage 3
        if (tid == 0)
            publish(s64 + b, red4[0] + red4[1] + red4[2] + red4[3] + aev, stag);

        // ---- stage 2: softmax (block-redundant) + c[u] ----
        if (tid == 0) waittag(s64 + 255, stag);
        __syncthreads();
        float sv = cohort_pull1(s64 + tid, stag);
        float m = sv;
#pragma unroll
        for (int off = 32; off > 0; off >>= 1) m = fmaxf(m, __shfl_down(m, off));
        if (lane == 0) red4b[wave] = m;
        __syncthreads();
        float mx = fmaxf(fmaxf(red4b[0], red4b[1]), fmaxf(red4b[2], red4b[3]));
        float ev = expf(sv - mx);
        a_s[tid] = ev;
        float ssum = ev;
#pragma unroll
        for (int off = 32; off > 0; off >>= 1) ssum += __shfl_down(ssum, off);
        __syncthreads();                 // readers of red4b (mx) done; a_s visible
        if (lane == 0) red4b[wave] = ssum;
        __syncthreads();
        float inv = 1.f / (red4b[0] + red4b[1] + red4b[2] + red4b[3]);
        float pc = fmaf(a_s[lane], rM[0], 0.f);
        pc = fmaf(a_s[lane + 64],  rM[1], pc);
        pc = fmaf(a_s[lane + 128], rM[2], pc);
        pc = fmaf(a_s[lane + 192], rM[3], pc);
#pragma unroll
        for (int off = 32; off > 0; off >>= 1) pc += __shfl_down(pc, off);
        if (lane == 0)
            publish(c64 + u, fmaxf(0.f, cpre + pc * inv), stag);

        // ---- stage 3: GRU cell ----
        if (tid < 4) waittag(c64 + 255 + (tid << 8), stag);
        __syncthreads();
        float c0, c1, c2, c3;
        cohort_pull4(c64 + tid, c64 + tid + 256, c64 + tid + 512, c64 + tid + 768,
                     stag, c0, c1, c2, c3);
        c_s[tid]       = c0;
        c_s[tid + 256] = c1;
        c_s[tid + 512] = c2;
        c_s[tid + 768] = c3;
        __syncthreads();
        float dir = 0.f, diz = 0.f, din = 0.f, dhr = 0.f, dhz = 0.f, dhn = 0.f;
#pragma unroll
        for (int i = 0; i < 16; ++i) {
            int k = lane + (i << 6);
            float cv = c_s[k], hv = h_s[p][k];
            dir = fmaf(rWir[i], cv, dir);
            diz = fmaf(rWiz[i], cv, diz);
            din = fmaf(rWin[i], cv, din);
            dhr = fmaf(rWhr[i], hv, dhr);
            dhz = fmaf(rWhz[i], hv, dhz);
            dhn = fmaf(rWhn[i], hv, dhn);
        }
#pragma unroll
        for (int off = 32; off > 0; off >>= 1) {
            dir += __shfl_down(dir, off); diz += __shfl_down(diz, off);
            din += __shfl_down(din, off); dhr += __shfl_down(dhr, off);
            dhz += __shfl_down(dhz, off); dhn += __shfl_down(dhn, off);
        }
        if (lane == 0) {
            float r = sigmoidf_(dir + bir + dhr + bhr);
            float z = sigmoidf_(diz + biz + dhz + bhz);
            float n = tanhf(din + bin_ + r * (dhn + bhn));
            float h2 = (1.f - z) * n + z * h_s[p][u];
            publish(h64 + ((t + 1) & 1) * H + u, h2, htag + 1);
            hs_dec[(size_t)t * H + u] = h2;
        }
    }
}

// ---------------------------------------------------------------------------
__global__ __launch_bounds__(256) void nll_kernel(
    const float* __restrict__ logits, const int* __restrict__ target_ids,
    float* __restrict__ nll)
{
    const int t = blockIdx.x, tid = threadIdx.x;
    __shared__ float red[256];
    const float* row = logits + (size_t)t * VOUT;
    float mx = -1e30f;
    for (int i = tid; i < VOUT; i += 256) mx = fmaxf(mx, row[i]);
    red[tid] = mx;
    __syncthreads();
    for (int off = 128; off > 0; off >>= 1) {
        if (tid < off) red[tid] = fmaxf(red[tid], red[tid + off]);
        __syncthreads();
    }
    mx = red[0];
    __syncthreads();
    float s = 0.f;
    for (int i = tid; i < VOUT; i += 256) s += expf(row[i] - mx);
    red[tid] = s;
    __syncthreads();
    for (int off = 128; off > 0; off >>= 1) {
        if (tid < off) red[tid] += red[tid + off];
        __syncthreads();
    }
    if (tid == 0) {
        float lse = mx + logf(red[0]);
        nll[t] = lse - row[target_ids[t]];
    }
}

__global__ __launch_bounds__(256) void sum_kernel(
    const float* __restrict__ nll, float* __restrict__ out)
{
    __shared__ float red[256];
    int tid = threadIdx.x;
    red[tid] = nll[tid];
    __syncthreads();
    for (int off = 128; off > 0; off >>= 1) {
        if (tid < off) red[tid] += red[tid + off];
        __syncthreads();
    }
    if (tid == 0) out[0] = red[0];
}

// ---------------------------------------------------------------------------
extern "C" void kernel_launch(void* const* d_in, const int* in_sizes, int n_in,
                              void* d_out, int out_size, void* d_ws, size_t ws_size,
                              hipStream_t stream)
{
    const int*   input_ids  = (const int*)d_in[0];
    const int*   target_ids = (const int*)d_in[1];
    const float* enc_emb = (const float*)d_in[2];
    const float* enc_Wi  = (const float*)d_in[3];
    const float* enc_Wh  = (const float*)d_in[4];
    const float* enc_bi  = (const float*)d_in[5];
    const float* enc_bh  = (const float*)d_in[6];
    const float* dec_emb = (const float*)d_in[7];
    const float* dec_Wi  = (const float*)d_in[8];
    const float* dec_Wh  = (const float*)d_in[9];
    const float* dec_bi  = (const float*)d_in[10];
    const float* dec_bh  = (const float*)d_in[11];
    const float* attn_W  = (const float*)d_in[12];
    const float* attn_b  = (const float*)d_in[13];
    const float* comb_W  = (const float*)d_in[14];
    const float* comb_b  = (const float*)d_in[15];
    const float* out_W   = (const float*)d_in[16];
    const float* out_b   = (const float*)d_in[17];
    float* out = (float*)d_out;

    float* ws = (float*)d_ws;
    float* enc_x    = ws; ws += SEQ * H;
    float* dec_e    = ws; ws += SEQ * H;
    float* enc_gi   = ws; ws += SEQ * 3 * H;
    float* attn_e   = ws; ws += SEQ * SEQ;
    float* comb_pre = ws; ws += SEQ * H;
    float* Mmat     = ws; ws += H * SEQ;
    float* encH     = ws; ws += SEQ * H;
    float* hs_dec   = ws; ws += SEQ * H;
    u64*   h64      = (u64*)ws; ws += 2 * H * 2;   // 2048 u64 (2 parities x H)
    u64*   s64      = (u64*)ws; ws += SEQ * 2;     // 256 u64
    u64*   c64      = (u64*)ws; ws += H * 2;       // 1024 u64
    float* nll      = ws; ws += SEQ;
    ws += (256 - ((ws - (float*)d_ws) & 255)) & 255;
    float* logits   = ws; ws += (size_t)SEQ * VOUT;

    // phase 0: gathers + init h slots (tag 0 = initial zero hidden state)
    hipLaunchKernelGGL(gather_kernel, dim3(512), dim3(256), 0, stream,
                       input_ids, target_ids, enc_emb, dec_emb, enc_x, dec_e);
    hipLaunchKernelGGL(init_kernel, dim3(8), dim3(256), 0, stream, h64);

    // phase 1: batched pre-GEMMs (M=256 -> grid.y=2 at 128-row tiles)
    hipLaunchKernelGGL(gemm_nt_kernel, dim3(3 * H / 64, SEQ / 128), dim3(256), 0, stream,
                       enc_x, enc_Wi, enc_bi, enc_gi, H, H, 0, H, 3 * H);
    hipLaunchKernelGGL(gemm_nt_kernel, dim3(SEQ / 64, SEQ / 128), dim3(256), 0, stream,
                       dec_e, attn_W, attn_b, attn_e, H, H, 0, 2 * H, SEQ);
    hipLaunchKernelGGL(gemm_nt_kernel, dim3(H / 64, SEQ / 128), dim3(256), 0, stream,
                       dec_e, comb_W, comb_b, comb_pre, H, H, 0, 2 * H, H);

    // phase 2: encoder recurrence (cooperative launch for residency guarantee)
    {
        void* args[] = {(void*)&enc_Wh, (void*)&enc_bh, (void*)&enc_gi,
                        (void*)&h64, (void*)&encH};
        hipLaunchCooperativeKernel((void*)enc_rnn_kernel, dim3(256), dim3(256),
                                   args, 0, stream);
    }

    // phase 2.5: M = comb_W[:,H:] @ encH^T   (M=1024 rows -> grid.y=8)
    hipLaunchKernelGGL(gemm_nt_kernel, dim3(SEQ / 64, H / 128), dim3(256), 0, stream,
                       comb_W, encH, (const float*)nullptr, Mmat, H, 2 * H, H, H, SEQ);

    // phase 3: decoder recurrence (h tags continue at 256 from encoder)
    {
        void* args[] = {(void*)&attn_W, (void*)&attn_e, (void*)&Mmat, (void*)&comb_pre,
                        (void*)&dec_Wi, (void*)&dec_Wh, (void*)&dec_bi, (void*)&dec_bh,
                        (void*)&h64, (void*)&s64, (void*)&c64, (void*)&hs_dec};
        hipLaunchCooperativeKernel((void*)dec_rnn_kernel, dim3(256), dim3(256),
                                   args, 0, stream);
    }

    // phase 4: logits = hs_dec @ out_W^T + out_b
    hipLaunchKernelGGL(gemm_nt_kernel, dim3(VOUT / 64, SEQ / 128), dim3(256), 0, stream,
                       hs_dec, out_W, out_b, logits, H, H, 0, H, VOUT);

    // phase 5: NLL + total
    hipLaunchKernelGGL(nll_kernel, dim3(SEQ), dim3(256), 0, stream,
                       logits, target_ids, nll);
    hipLaunchKernelGGL(sum_kernel, dim3(1), dim3(256), 0, stream, nll, out);
}